// Round 4
// baseline (199.517 us; speedup 1.0000x reference)
//
#include <hip/hip_runtime.h>

#define NUM_LABELS 1025
#define LBIN (NUM_LABELS * 4)        // LDS u64 slots: 4100 * 8B = 32800 B
#define GSTRIDE 5                    // global u64 slots per (batch,label): A,B,C,D,E
static constexpr int HW = 1024 * 1024;
static constexpr int NBATCH = 8;
static constexpr float LINE_THRESH = 63.75f;     // 255/4
static constexpr int NSEG = NBATCH * NUM_LABELS; // 8200
static constexpr float QSCALE = 16384.0f;        // 2^14 fixed point
static constexpr float INVQ   = 1.0f / 16384.0f;
typedef unsigned long long u64;
typedef unsigned int u32;

// K1: one pass; each block serves ONE batch. LDS u64 histogram, label-only key.
// Per label, 4 u64 slots (physical index swizzled by lab bits for bank spread):
//   slot0 (a01): lo = sum(q0) + count<<24      hi = sum(q1) mod 2^32
//   slot1 (a23): lo = sum(q2)                  hi = sum(q3)
//   slot2 (m01): same as slot0 but wl==0 subset (count = M)
//   slot3 (m23): same as slot1 but wl==0 subset
// lo halves stay positive & < 2^31 (count<<24 dominates |sum q| <= n*90112),
// so u64 adds never carry/borrow across the 32-bit boundary.
// Flush: decode per-slice, re-bias counts at 2^18, accumulate into the tiny
// global histogram with u64 atomics (integer => order-independent => exact).
__global__ __launch_bounds__(512) void spx_k1(
    const float* __restrict__ Is, const int* __restrict__ Ispp,
    const float* __restrict__ Il, u64* __restrict__ gbins,
    float* __restrict__ a_g, int bpb)
{
    __shared__ u64 bins[LBIN];
    const int t = threadIdx.x;
    for (int i = t; i < LBIN; i += 512) bins[i] = 0ull;
    __syncthreads();

    const int b   = blockIdx.x / bpb;
    const int blk = blockIdx.x % bpb;
    const long long planeI = (long long)b * HW;
    const long long chan0  = (long long)(b * 4) * HW;

    float a = 0.f;
    const int QB = HW >> 2;                    // 262144 quads per batch
#pragma unroll 2
    for (int q = blk * 512 + t; q < QB; q += bpb * 512) {
        const int pix = q << 2;

        const int4   lab4 = *(const int4*)(Ispp + planeI + pix);
        const float4 il4  = *(const float4*)(Il + planeI + pix);
        float4 ch[4];
#pragma unroll
        for (int c = 0; c < 4; ++c)
            ch[c] = *(const float4*)(Is + chan0 + (long long)c * HW + pix);

        const int*   lab = (const int*)&lab4;
        const float* il  = (const float*)&il4;
        const float* f0  = (const float*)&ch[0];
        const float* f1  = (const float*)&ch[1];
        const float* f2  = (const float*)&ch[2];
        const float* f3  = (const float*)&ch[3];

#pragma unroll
        for (int j = 0; j < 4; ++j) {
            const float v0 = f0[j], v1 = f1[j], v2 = f2[j], v3 = f3[j];
            const int q0 = __float2int_rn(v0 * QSCALE);
            const int q1 = __float2int_rn(v1 * QSCALE);
            const int q2 = __float2int_rn(v2 * QSCALE);
            const int q3 = __float2int_rn(v3 * QSCALE);
            const u64 a01 = ((u64)(u32)q1 << 32) | (u32)(q0 + (1 << 24));
            const u64 a23 = ((u64)(u32)q3 << 32) | (u32)q2;
            const int L = lab[j];
            const int p = (L >> 2) & 3;        // bank-spread swizzle
            const int base = L * 4;
            atomicAdd(&bins[base + (0 ^ p)], a01);
            atomicAdd(&bins[base + (1 ^ p)], a23);
            if (il[j] > LINE_THRESH) {
                a += v0 * v0 + v1 * v1 + v2 * v2 + v3 * v3;
            } else {
                atomicAdd(&bins[base + (2 ^ p)], a01);
                atomicAdd(&bins[base + (3 ^ p)], a23);
            }
        }
    }
    __syncthreads();

    // decode + flush into global per-batch histogram
    u64* gb = gbins + (size_t)b * NUM_LABELS * GSTRIDE;
    for (int L = t; L < NUM_LABELS; L += 512) {
        const int p = (L >> 2) & 3;
        const int base = L * 4;
        const u64 va = bins[base + (0 ^ p)];
        const u64 vb = bins[base + (1 ^ p)];
        const u64 vm = bins[base + (2 ^ p)];
        const u64 vn = bins[base + (3 ^ p)];

        const u32 alo = (u32)va;
        const u32 n   = (alo + (1u << 23)) >> 24;
        const int s0  = (int)(alo - (n << 24));
        const int s1  = (int)(va >> 32);
        const int s2  = (int)(u32)vb;
        const int s3  = (int)(vb >> 32);
        const u32 mlo = (u32)vm;
        const u32 m   = (mlo + (1u << 23)) >> 24;
        const int u0  = (int)(mlo - (m << 24));
        const int u1  = (int)(vm >> 32);
        const int u2  = (int)(u32)vn;
        const int u3  = (int)(vn >> 32);

        if (n) {
            atomicAdd(&gb[L * GSTRIDE + 0],
                      ((u64)(u32)s1 << 32) | (u32)(s0 + (int)(n << 18)));
            atomicAdd(&gb[L * GSTRIDE + 1],
                      ((u64)(u32)s3 << 32) | (u32)(s2 + (int)(n << 18)));
            atomicAdd(&gb[L * GSTRIDE + 2], (u64)n | ((u64)m << 32));
            if (m) {
                atomicAdd(&gb[L * GSTRIDE + 3],
                          ((u64)(u32)u1 << 32) | (u32)(u0 + (int)(m << 18)));
                atomicAdd(&gb[L * GSTRIDE + 4],
                          ((u64)(u32)u3 << 32) | (u32)(u2 + (int)(m << 18)));
            }
        }
    }

    // deterministic per-block reduce of A
#pragma unroll
    for (int off = 32; off >= 1; off >>= 1) a += __shfl_xor(a, off, 64);
    __shared__ float apart[8];
    if ((t & 63) == 0) apart[t >> 6] = a;
    __syncthreads();
    if (t == 0) {
        float s = 0.f;
#pragma unroll
        for (int w = 0; w < 8; ++w) s += apart[w];
        a_g[blockIdx.x] = s;
    }
}

// K23: single block. Decode global histogram -> per-segment correction,
// sum with A partials (fixed order => deterministic), divide, write out.
__global__ __launch_bounds__(1024) void spx_k23(
    const u64* __restrict__ gbins, const float* __restrict__ a_g, int SL,
    float* __restrict__ out)
{
    float acc = 0.f;
    for (int s = threadIdx.x; s < NSEG; s += 1024) {
        const int L = s % NUM_LABELS;
        if (L == 0) continue;
        const u64* p = gbins + (size_t)s * GSTRIDE;
        const u64 A = p[0], B = p[1], C = p[2], D = p[3], E = p[4];
        const int n = (int)(u32)C;
        const int m = (int)(C >> 32);
        const float S[4] = {
            (float)((int)(u32)A - (n << 18)) * INVQ,
            (float)((int)(A >> 32)) * INVQ,
            (float)((int)(u32)B - (n << 18)) * INVQ,
            (float)((int)(B >> 32)) * INVQ };
        const float U[4] = {
            (float)((int)(u32)D - (m << 18)) * INVQ,
            (float)((int)(D >> 32)) * INVQ,
            (float)((int)(u32)E - (m << 18)) * INVQ,
            (float)((int)(E >> 32)) * INVQ };
        const float inv = 1.f / fmaxf((float)n, 1.f);
        const float t3  = (float)(n - m);
#pragma unroll
        for (int c = 0; c < 4; ++c) {
            const float mean = S[c] * inv;
            const float t2   = S[c] - U[c];
            acc += t3 * mean * mean - 2.f * mean * t2;
        }
    }
    for (int i = threadIdx.x; i < SL; i += 1024) acc += a_g[i];

    __shared__ float red[1024];
    red[threadIdx.x] = acc;
    __syncthreads();
    for (int off = 512; off >= 1; off >>= 1) {
        if (threadIdx.x < (unsigned)off) red[threadIdx.x] += red[threadIdx.x + off];
        __syncthreads();
    }
    if (threadIdx.x == 0) out[0] = red[0] / 8388608.0f;
}

extern "C" void kernel_launch(void* const* d_in, const int* in_sizes, int n_in,
                              void* d_out, int out_size, void* d_ws, size_t ws_size,
                              hipStream_t stream)
{
    const float* Is   = (const float*)d_in[0];
    const int*   Ispp = (const int*)d_in[1];
    const float* Il   = (const float*)d_in[2];
    float* out = (float*)d_out;

    const size_t gbins_bytes = (size_t)NSEG * GSTRIDE * 8;   // 328 KB
    int SL = 1024;                       // K1 blocks; multiple of 8 batches
    while (SL > 8 && gbins_bytes + (size_t)SL * 4 > ws_size) SL >>= 1;
    const int bpb = SL / NBATCH;

    u64*   gbins = (u64*)d_ws;
    float* a_g   = (float*)((char*)d_ws + gbins_bytes);

    hipMemsetAsync(gbins, 0, gbins_bytes, stream);
    spx_k1<<<SL, 512, 0, stream>>>(Is, Ispp, Il, gbins, a_g, bpb);
    spx_k23<<<1, 1024, 0, stream>>>(gbins, a_g, SL, out);
}

// Round 5
// 55.628 us; speedup vs baseline: 3.5866x; 3.5866x over previous
//
#include <hip/hip_runtime.h>

#define NUM_LABELS 1025
#define STRIDE 9                           // LDS dwords per label; gcd(9,32)=1 spreads banks
#define NBIN (NUM_LABELS * STRIDE)         // 9225 dwords = 36.9 KB LDS per block
#define GROUP 8                            // compact dwords per label in global slices
static constexpr int HW = 1024 * 1024;
static constexpr int NBATCH = 8;
static constexpr float LINE_THRESH = 63.75f;     // 255/4
static constexpr int NSEG = NBATCH * NUM_LABELS; // 8200
static constexpr float QSCALE = 16384.0f;        // 2^14 fixed point
static constexpr float INVQ   = 1.0f / 16384.0f;
typedef unsigned int u32;

// K1: one pass; each block serves ONE batch; label-only LDS u32 histogram.
//   bins[lab*9 + 0..3] : unmasked fixed-point sums; +0 embeds count<<24
//   bins[lab*9 + 4..7] : wl==0 subset sums;         +4 embeds mcount<<24
// a = sum over wl==1 pixels of sum_c x^2 (f32, deterministic block reduce).
// 1024-thread blocks: SL=512 slices but 32 waves/CU (2 blocks x 16 waves).
__global__ __launch_bounds__(1024) void spx_k1(
    const float* __restrict__ Is, const int* __restrict__ Ispp,
    const float* __restrict__ Il, int* __restrict__ bins_g,
    float* __restrict__ a_g, int bpb)
{
    __shared__ int bins[NBIN];
    const int t = threadIdx.x;
    for (int i = t; i < NBIN; i += 1024) bins[i] = 0;
    __syncthreads();

    const int b   = blockIdx.x / bpb;
    const int blk = blockIdx.x % bpb;
    const long long planeI = (long long)b * HW;
    const long long chan0  = (long long)(b * 4) * HW;

    float a = 0.f;
    const int QB = HW >> 2;                    // 262144 quads per batch
#pragma unroll 2
    for (int q = blk * 1024 + t; q < QB; q += bpb * 1024) {
        const int pix = q << 2;

        const int4   lab4 = *(const int4*)(Ispp + planeI + pix);
        const float4 il4  = *(const float4*)(Il + planeI + pix);
        float4 ch[4];
#pragma unroll
        for (int c = 0; c < 4; ++c)
            ch[c] = *(const float4*)(Is + chan0 + (long long)c * HW + pix);

        const int*   lab = (const int*)&lab4;
        const float* il  = (const float*)&il4;
        const float* f0  = (const float*)&ch[0];
        const float* f1  = (const float*)&ch[1];
        const float* f2  = (const float*)&ch[2];
        const float* f3  = (const float*)&ch[3];

#pragma unroll
        for (int j = 0; j < 4; ++j) {
            const float v0 = f0[j], v1 = f1[j], v2 = f2[j], v3 = f3[j];
            const int base = lab[j] * STRIDE;
            const int q0 = __float2int_rn(v0 * QSCALE) + (1 << 24);
            const int q1 = __float2int_rn(v1 * QSCALE);
            const int q2 = __float2int_rn(v2 * QSCALE);
            const int q3 = __float2int_rn(v3 * QSCALE);
            atomicAdd(&bins[base + 0], q0);
            atomicAdd(&bins[base + 1], q1);
            atomicAdd(&bins[base + 2], q2);
            atomicAdd(&bins[base + 3], q3);
            if (il[j] > LINE_THRESH) {
                a += v0 * v0 + v1 * v1 + v2 * v2 + v3 * v3;
            } else {
                atomicAdd(&bins[base + 4], q0);
                atomicAdd(&bins[base + 5], q1);
                atomicAdd(&bins[base + 6], q2);
                atomicAdd(&bins[base + 7], q3);
            }
        }
    }
    __syncthreads();

    // compact flush: 8 dwords per label (coalesced global writes)
    int* dst = bins_g + (size_t)blockIdx.x * (NUM_LABELS * GROUP);
    for (int i = t; i < NUM_LABELS * GROUP; i += 1024)
        dst[i] = bins[(i >> 3) * STRIDE + (i & 7)];

    // deterministic block reduce of A
#pragma unroll
    for (int off = 32; off >= 1; off >>= 1) a += __shfl_xor(a, off, 64);
    __shared__ float apart[16];
    if ((t & 63) == 0) apart[t >> 6] = a;
    __syncthreads();
    if (t == 0) {
        float s = 0.f;
#pragma unroll
        for (int w = 0; w < 16; ++w) s += apart[w];
        a_g[blockIdx.x] = s;
    }
}

// K2: per segment, decode+reduce the batch's slices, emit correction:
//   corr_s = sum_c ( T3*m_c^2 - 2*m_c*T2_c ),  m = S/N, T2 = S-U, T3 = N-M
__global__ __launch_bounds__(256) void spx_k2(
    const int* __restrict__ bins_g, int bpb, float* __restrict__ corr)
{
    const int lane = threadIdx.x & 63;
    const int s = blockIdx.x * 4 + (threadIdx.x >> 6);   // NSEG = 2050*4
    const int b   = s / NUM_LABELS;
    const int lab = s % NUM_LABELS;

    // v: S0..S3, N, U0..U3, M
    float v[10];
#pragma unroll
    for (int j = 0; j < 10; ++j) v[j] = 0.f;

    for (int k = lane; k < bpb; k += 64) {
        const int* p = bins_g + (size_t)(b * bpb + k) * (NUM_LABELS * GROUP)
                     + lab * GROUP;
        const int4 wa = *(const int4*)(p);
        const int4 wb = *(const int4*)(p + 4);

        const u32 cN = ((u32)(wa.x + (1 << 23))) >> 24;
        const int s0 = wa.x - (int)(cN << 24);
        const u32 cM = ((u32)(wb.x + (1 << 23))) >> 24;
        const int u0 = wb.x - (int)(cM << 24);

        v[0] += (float)s0   * INVQ;
        v[1] += (float)wa.y * INVQ;
        v[2] += (float)wa.z * INVQ;
        v[3] += (float)wa.w * INVQ;
        v[4] += (float)cN;
        v[5] += (float)u0   * INVQ;
        v[6] += (float)wb.y * INVQ;
        v[7] += (float)wb.z * INVQ;
        v[8] += (float)wb.w * INVQ;
        v[9] += (float)cM;
    }
#pragma unroll
    for (int off = 32; off >= 1; off >>= 1) {
#pragma unroll
        for (int j = 0; j < 10; ++j) v[j] += __shfl_xor(v[j], off, 64);
    }

    if (lane == 0) {
        float c = 0.f;
        if (lab != 0) {
            const float inv = 1.f / fmaxf(v[4], 1.f);
            const float t3  = v[4] - v[9];
#pragma unroll
            for (int j = 0; j < 4; ++j) {
                const float m  = v[j] * inv;
                const float t2 = v[j] - v[5 + j];
                c += t3 * m * m - 2.f * m * t2;
            }
        }
        corr[s] = c;
    }
}

// K3: out = (sum(corr) + sum(A partials)) / NPIX, deterministic
__global__ __launch_bounds__(1024) void spx_k3(
    const float* __restrict__ corr, const float* __restrict__ a_g, int SL,
    float* __restrict__ out)
{
    __shared__ float red[1024];
    float s = 0.f;
    for (int i = threadIdx.x; i < NSEG; i += 1024) s += corr[i];
    for (int i = threadIdx.x; i < SL;   i += 1024) s += a_g[i];
    red[threadIdx.x] = s;
    __syncthreads();
    for (int off = 512; off >= 1; off >>= 1) {
        if (threadIdx.x < (unsigned)off) red[threadIdx.x] += red[threadIdx.x + off];
        __syncthreads();
    }
    if (threadIdx.x == 0) out[0] = red[0] / 8388608.0f;
}

extern "C" void kernel_launch(void* const* d_in, const int* in_sizes, int n_in,
                              void* d_out, int out_size, void* d_ws, size_t ws_size,
                              hipStream_t stream)
{
    const float* Is   = (const float*)d_in[0];
    const int*   Ispp = (const int*)d_in[1];
    const float* Il   = (const float*)d_in[2];
    float* out = (float*)d_out;

    int SL = 512;                       // K1 blocks (slices); multiple of 8
    while (SL > 8 &&
           ((size_t)SL * NUM_LABELS * GROUP * 4 + (size_t)SL * 4
            + (size_t)NSEG * 4) > ws_size)
        SL >>= 1;
    const int bpb = SL / NBATCH;

    int*   bins_g = (int*)d_ws;
    float* a_g    = (float*)(bins_g + (size_t)SL * NUM_LABELS * GROUP);
    float* corr   = a_g + SL;

    spx_k1<<<SL, 1024, 0, stream>>>(Is, Ispp, Il, bins_g, a_g, bpb);
    spx_k2<<<NSEG / 4, 256, 0, stream>>>(bins_g, bpb, corr);
    spx_k3<<<1, 1024, 0, stream>>>(corr, a_g, SL, out);
}